// Round 5
// baseline (1358.252 us; speedup 1.0000x reference)
//
#include <hip/hip_runtime.h>

// relu(x @ W^T + b): M=131072, K=256, N=256, f32 in/out.
// R9: occupancy lever. R8 counters: MfmaUtil 21 / VALU 21 / HBM 27 / occ 27%
// -> all pipes idle; demand arithmetic says ~22% utilization == measured, so
// the machine is TLP-starved (12 waves/CU), not schedule-bound.
// Change: BN=256 (whole N per block), 512 threads = 8 waves (2x4), each wave
// the SAME 64x64 2x2-fragment workload as R8. x-tile/LDS unchanged (48 KB,
// 3 buffers) -> still 3 blocks/CU but 24 waves/CU (6/SIMD) vs 12. Also kills
// ct-redundant x staging. Counted-vmcnt schedule kept: per chunk
// vmcnt(2) -> raw barrier -> B-loads -> STAGE(c+2) -> compute; never drain.
// Math identical to verified R7/R8 (absmax 0.015625): W pre-split hi/lo bf16
// fragment-order; x staged f32, both-sides XOR swizzle; out = xh*wh + xh*wl
// + xl*wh via mfma_f32_32x32x16_bf16, fp32 acc.

typedef __attribute__((ext_vector_type(16))) float f32x16;
typedef __attribute__((ext_vector_type(8))) __bf16 bf16x8;

#define MFMA(a, b, c) \
    (c) = __builtin_amdgcn_mfma_f32_32x32x16_bf16((a), (b), (c), 0, 0, 0)

// Truncation split of 8 f32 into hi/lo bf16x8 fragments (verified R6-R8).
__device__ __forceinline__ void cvt8(const float4& A, const float4& B,
                                     bf16x8& hi, bf16x8& lo) {
    const float f[8] = {A.x, A.y, A.z, A.w, B.x, B.y, B.z, B.w};
#pragma unroll
    for (int j = 0; j < 8; ++j) {
        const unsigned int u = __builtin_bit_cast(unsigned int, f[j]);
        hi[j] = __builtin_bit_cast(__bf16, (unsigned short)(u >> 16));
        const float hf = __builtin_bit_cast(float, u & 0xffff0000u);
        const float lf = f[j] - hf;
        lo[j] = __builtin_bit_cast(__bf16,
                    (unsigned short)(__builtin_bit_cast(unsigned int, lf) >> 16));
    }
}

__device__ __forceinline__ void gload16(const float* g, float* l) {
    __builtin_amdgcn_global_load_lds(
        (const __attribute__((address_space(1))) void*)g,
        (__attribute__((address_space(3))) void*)l, 16, 0, 0);
}

// ---------------- W prep: f32 -> hi/lo bf16 in B-fragment order -------------
// Fragment F = col/32 (0..7); layout [F][t][lane] : (F*16+t)*512 + lane*8.
__global__ __launch_bounds__(256)
void wprep_kernel(const float* __restrict__ W,
                  __bf16* __restrict__ whi, __bf16* __restrict__ wlo) {
    const int wv = (int)blockIdx.x * 4 + (threadIdx.x >> 6);   // 0..127
    const int l  = threadIdx.x & 63;
    const int t  = wv & 15;          // k-step
    const int F  = wv >> 4;          // column fragment 0..7
    const int n  = F * 32 + (l & 31);
    const int k  = t * 16 + (l >> 5) * 8;
    const float4 A = *(const float4*)(W + n * 256 + k);
    const float4 B = *(const float4*)(W + n * 256 + k + 4);
    bf16x8 hi, lo;
    cvt8(A, B, hi, lo);
    *(bf16x8*)(whi + wv * 512 + l * 8) = hi;
    *(bf16x8*)(wlo + wv * 512 + l * 8) = lo;
}

// ---------------- main GEMM -------------------------------------------------
__global__ __launch_bounds__(512, 6)
void gemm_mfma_kernel(const float* __restrict__ x,
                      const __bf16* __restrict__ whi,
                      const __bf16* __restrict__ wlo,
                      const float* __restrict__ bias,
                      float* __restrict__ out) {
    // 3 buffers x 128 rows x 32 f32 = 48 KB
    __shared__ float xs[3][4096];

    const int tid  = threadIdx.x;       // 0..511
    const int lane = tid & 63;
    const int wid  = tid >> 6;          // 0..7
    const int wm   = wid >> 2;          // 0/1
    const int wn   = wid & 3;           // 0..3

    // XCD swizzle: 1024 blocks, 8 XCDs, 1024%8==0 -> simple bijective form.
    const int bid = (int)blockIdx.x;
    const int rt  = (bid & 7) * 128 + (bid >> 3);

    const int r31 = lane & 31;
    const int g   = lane >> 5;
    const long row0 = (long)rt * 128;

    const int m0 = wm * 64 + r31;
    const int m1 = m0 + 32;
    const int sw = r31 & 7;

    f32x16 acc[2][2];
#pragma unroll
    for (int i = 0; i < 2; ++i)
#pragma unroll
        for (int j = 0; j < 2; ++j)
#pragma unroll
            for (int r = 0; r < 16; ++r) acc[i][j][r] = 0.f;

    const int fbase0 = (wn * 2) * 16;   // first of this wave's 2 col-fragments
    const __bf16* whip = whi + (long)lane * 8;
    const __bf16* wlop = wlo + (long)lane * 8;

    // Stage one BK=32 chunk (128 rows x 32 f32 = 1024 granules of 16B).
    // 512 threads -> 2 gload_lds per thread. Linear LDS dest, swizzled source.
    auto STAGE = [&](int b, int chunk) {
#pragma unroll
        for (int j = 0; j < 2; ++j) {
            const int G = j * 512 + tid;             // granule id 0..1023
            const int m = G >> 3;                    // tile row 0..127
            const int cs = (G & 7) ^ (m & 7);        // swizzled source granule
            const float* gp = x + (row0 + m) * 256 + chunk * 32 + cs * 4;
            float* lp = &xs[b][(j * 512 + wid * 64) * 4];   // wave-uniform base
            gload16(gp, lp);
        }
    };

    // One t-step (k-width 16) of MFMA work from buffer xb.
    auto TSTEP = [&](const float* xb, int t,
                     const bf16x8& bh0, const bf16x8& bl0,
                     const bf16x8& bh1, const bf16x8& bl1) {
        const int c0 = t * 4 + g * 2;
        const float4 A0a = *(const float4*)(xb + m0 * 32 + ((c0 ^ sw) * 4));
        const float4 A0b = *(const float4*)(xb + m0 * 32 + (((c0 + 1) ^ sw) * 4));
        const float4 A1a = *(const float4*)(xb + m1 * 32 + ((c0 ^ sw) * 4));
        const float4 A1b = *(const float4*)(xb + m1 * 32 + (((c0 + 1) ^ sw) * 4));
        bf16x8 ah0, al0, ah1, al1;
        cvt8(A0a, A0b, ah0, al0);
        cvt8(A1a, A1b, ah1, al1);
        MFMA(ah0, bh0, acc[0][0]); MFMA(ah0, bh1, acc[0][1]);
        MFMA(ah1, bh0, acc[1][0]); MFMA(ah1, bh1, acc[1][1]);
        MFMA(ah0, bl0, acc[0][0]); MFMA(ah0, bl1, acc[0][1]);
        MFMA(ah1, bl0, acc[1][0]); MFMA(ah1, bl1, acc[1][1]);
        MFMA(al0, bh0, acc[0][0]); MFMA(al0, bh1, acc[0][1]);
        MFMA(al1, bh0, acc[1][0]); MFMA(al1, bh1, acc[1][1]);
    };

    // Per-chunk phase: wait(buf c ready, keep newer in flight) -> raw barrier
    // -> B-loads (issued OLDER than next STAGE) -> STAGE(c+2) -> compute.
#define CHUNK(c, VM)                                                          \
    {                                                                         \
        asm volatile("s_waitcnt vmcnt(" VM ")" ::: "memory");                 \
        __builtin_amdgcn_s_barrier();                                         \
        const long f0 = (long)(fbase0 + (c) * 2) * 512;                       \
        const long f1 = f0 + 16 * 512;                                        \
        const long h0 = (long)(fbase0 + (c) * 2 + 1) * 512;                   \
        const long h1 = h0 + 16 * 512;                                        \
        const bf16x8 B0h0 = *(const bf16x8*)(whip + f0);                      \
        const bf16x8 B0l0 = *(const bf16x8*)(wlop + f0);                      \
        const bf16x8 B0h1 = *(const bf16x8*)(whip + f1);                      \
        const bf16x8 B0l1 = *(const bf16x8*)(wlop + f1);                      \
        const bf16x8 B1h0 = *(const bf16x8*)(whip + h0);                      \
        const bf16x8 B1l0 = *(const bf16x8*)(wlop + h0);                      \
        const bf16x8 B1h1 = *(const bf16x8*)(whip + h1);                      \
        const bf16x8 B1l1 = *(const bf16x8*)(wlop + h1);                      \
        __builtin_amdgcn_sched_barrier(0);                                    \
        if ((c) + 2 < 8) STAGE(((c) + 2) % 3, (c) + 2);                       \
        const float* xb = &xs[(c) % 3][0];                                    \
        TSTEP(xb, 0, B0h0, B0l0, B0h1, B0l1);                                 \
        TSTEP(xb, 1, B1h0, B1l0, B1h1, B1l1);                                 \
    }

    STAGE(0, 0);
    STAGE(1, 1);
    CHUNK(0, "2")
    CHUNK(1, "2")
    CHUNK(2, "2")
    CHUNK(3, "2")
    CHUNK(4, "2")
    CHUNK(5, "2")
    CHUNK(6, "2")
    CHUNK(7, "0")
#undef CHUNK

    // Epilogue: bias + ReLU. C/D map (verified m74/m101):
    // col = lane&31, row = (r&3) + 8*(r>>2) + 4*(lane>>5).
    const int  ocol0 = wn * 64;
    const long orow0 = row0 + wm * 64;
    const float bj0 = bias[ocol0 + r31];
    const float bj1 = bias[ocol0 + 32 + r31];

#pragma unroll
    for (int i = 0; i < 2; ++i) {
#pragma unroll
        for (int r = 0; r < 16; ++r) {
            const int rowf = (r & 3) + 8 * (r >> 2) + 4 * g;
            const long row = orow0 + i * 32 + rowf;
            float v0 = acc[i][0][r] + bj0;
            float v1 = acc[i][1][r] + bj1;
            v0 = v0 > 0.f ? v0 : 0.f;
            v1 = v1 > 0.f ? v1 : 0.f;
            out[row * 256 + ocol0 + r31]      = v0;
            out[row * 256 + ocol0 + 32 + r31] = v1;
        }
    }
}

extern "C" void kernel_launch(void* const* d_in, const int* in_sizes, int n_in,
                              void* d_out, int out_size, void* d_ws, size_t ws_size,
                              hipStream_t stream) {
    (void)n_in; (void)ws_size; (void)out_size;
    const float* x = (const float*)d_in[0];
    const float* W = (const float*)d_in[1];
    const float* b = (const float*)d_in[2];
    float* out = (float*)d_out;

    __bf16* whi = (__bf16*)d_ws;             // 128 KB
    __bf16* wlo = whi + 65536;               // 128 KB

    wprep_kernel<<<32, 256, 0, stream>>>(W, whi, wlo);

    const int M = in_sizes[0] / 256;         // 131072
    const int grid = M / 128;                // 1024 row tiles, whole N each
    gemm_mfma_kernel<<<grid, 512, 0, stream>>>(x, whi, wlo, b, out);
}

// Round 6
// 263.583 us; speedup vs baseline: 5.1530x; 5.1530x over previous
//
#include <hip/hip_runtime.h>

// relu(x @ W^T + b): M=131072, K=256, N=256, f32 in/out.
// R10: R9 structure with the register budget fixed. R9's __launch_bounds__
// (512, 6) was interpreted CUDA-style (6 BLOCKS/CU = 12 waves/SIMD) ->
// VGPR capped at 40 -> 64-reg accumulator spilled to scratch (WRITE_SIZE
// 3.6 GB, MfmaUtil 0.2%). Fix: (512, 3) -> 6 waves/SIMD -> cap ~85 VGPR,
// >= the 80 this per-thread code measured in R8. Guarantees 3 blocks/CU
// (24 waves/CU, double R8's 12) with zero spill.
// Structure (unchanged from R9): BN=256 whole-N blocks, 8 waves (2x4),
// each wave a 64x64 2x2-fragment tile; x staged once per row-tile (no
// ct duplication); 3 LDS buffers (48 KB), counted-vmcnt schedule
// (vmcnt(2) -> raw barrier -> B-loads -> STAGE(c+2) -> compute, never
// drain in-loop); XCD-bijective block swizzle (1024 % 8 == 0).
// Math identical to verified R7-R9 (absmax 0.015625): W pre-split hi/lo
// bf16 fragment-order; x staged f32, both-sides XOR swizzle;
// out = xh*wh + xh*wl + xl*wh via mfma_f32_32x32x16_bf16, fp32 acc.

typedef __attribute__((ext_vector_type(16))) float f32x16;
typedef __attribute__((ext_vector_type(8))) __bf16 bf16x8;

#define MFMA(a, b, c) \
    (c) = __builtin_amdgcn_mfma_f32_32x32x16_bf16((a), (b), (c), 0, 0, 0)

// Truncation split of 8 f32 into hi/lo bf16x8 fragments (verified R6-R9).
__device__ __forceinline__ void cvt8(const float4& A, const float4& B,
                                     bf16x8& hi, bf16x8& lo) {
    const float f[8] = {A.x, A.y, A.z, A.w, B.x, B.y, B.z, B.w};
#pragma unroll
    for (int j = 0; j < 8; ++j) {
        const unsigned int u = __builtin_bit_cast(unsigned int, f[j]);
        hi[j] = __builtin_bit_cast(__bf16, (unsigned short)(u >> 16));
        const float hf = __builtin_bit_cast(float, u & 0xffff0000u);
        const float lf = f[j] - hf;
        lo[j] = __builtin_bit_cast(__bf16,
                    (unsigned short)(__builtin_bit_cast(unsigned int, lf) >> 16));
    }
}

__device__ __forceinline__ void gload16(const float* g, float* l) {
    __builtin_amdgcn_global_load_lds(
        (const __attribute__((address_space(1))) void*)g,
        (__attribute__((address_space(3))) void*)l, 16, 0, 0);
}

// ---------------- W prep: f32 -> hi/lo bf16 in B-fragment order -------------
// Fragment F = col/32 (0..7); layout [F][t][lane] : (F*16+t)*512 + lane*8.
__global__ __launch_bounds__(256)
void wprep_kernel(const float* __restrict__ W,
                  __bf16* __restrict__ whi, __bf16* __restrict__ wlo) {
    const int wv = (int)blockIdx.x * 4 + (threadIdx.x >> 6);   // 0..127
    const int l  = threadIdx.x & 63;
    const int t  = wv & 15;          // k-step
    const int F  = wv >> 4;          // column fragment 0..7
    const int n  = F * 32 + (l & 31);
    const int k  = t * 16 + (l >> 5) * 8;
    const float4 A = *(const float4*)(W + n * 256 + k);
    const float4 B = *(const float4*)(W + n * 256 + k + 4);
    bf16x8 hi, lo;
    cvt8(A, B, hi, lo);
    *(bf16x8*)(whi + wv * 512 + l * 8) = hi;
    *(bf16x8*)(wlo + wv * 512 + l * 8) = lo;
}

// ---------------- main GEMM -------------------------------------------------
// (512, 3): hipcc CUDA-style minBlocksPerCU=3 -> 6 waves/SIMD -> VGPR cap
// ~85 (this code needs ~80, measured R8). Do NOT raise the 2nd arg: 6
// capped VGPR at 40 and spilled the 64-reg accumulator (R9 post-mortem).
__global__ __launch_bounds__(512, 3)
void gemm_mfma_kernel(const float* __restrict__ x,
                      const __bf16* __restrict__ whi,
                      const __bf16* __restrict__ wlo,
                      const float* __restrict__ bias,
                      float* __restrict__ out) {
    // 3 buffers x 128 rows x 32 f32 = 48 KB
    __shared__ float xs[3][4096];

    const int tid  = threadIdx.x;       // 0..511
    const int lane = tid & 63;
    const int wid  = tid >> 6;          // 0..7
    const int wm   = wid >> 2;          // 0/1
    const int wn   = wid & 3;           // 0..3

    // XCD swizzle: 1024 blocks, 8 XCDs, 1024%8==0 -> simple bijective form.
    const int bid = (int)blockIdx.x;
    const int rt  = (bid & 7) * 128 + (bid >> 3);

    const int r31 = lane & 31;
    const int g   = lane >> 5;
    const long row0 = (long)rt * 128;

    const int m0 = wm * 64 + r31;
    const int m1 = m0 + 32;
    const int sw = r31 & 7;

    f32x16 acc[2][2];
#pragma unroll
    for (int i = 0; i < 2; ++i)
#pragma unroll
        for (int j = 0; j < 2; ++j)
#pragma unroll
            for (int r = 0; r < 16; ++r) acc[i][j][r] = 0.f;

    const int fbase0 = (wn * 2) * 16;   // first of this wave's 2 col-fragments
    const __bf16* whip = whi + (long)lane * 8;
    const __bf16* wlop = wlo + (long)lane * 8;

    // Stage one BK=32 chunk (128 rows x 32 f32 = 1024 granules of 16B).
    // 512 threads -> 2 gload_lds per thread. Linear LDS dest, swizzled source.
    auto STAGE = [&](int b, int chunk) {
#pragma unroll
        for (int j = 0; j < 2; ++j) {
            const int G = j * 512 + tid;             // granule id 0..1023
            const int m = G >> 3;                    // tile row 0..127
            const int cs = (G & 7) ^ (m & 7);        // swizzled source granule
            const float* gp = x + (row0 + m) * 256 + chunk * 32 + cs * 4;
            float* lp = &xs[b][(j * 512 + wid * 64) * 4];   // wave-uniform base
            gload16(gp, lp);
        }
    };

    // One t-step (k-width 16) of MFMA work from buffer xb.
    auto TSTEP = [&](const float* xb, int t,
                     const bf16x8& bh0, const bf16x8& bl0,
                     const bf16x8& bh1, const bf16x8& bl1) {
        const int c0 = t * 4 + g * 2;
        const float4 A0a = *(const float4*)(xb + m0 * 32 + ((c0 ^ sw) * 4));
        const float4 A0b = *(const float4*)(xb + m0 * 32 + (((c0 + 1) ^ sw) * 4));
        const float4 A1a = *(const float4*)(xb + m1 * 32 + ((c0 ^ sw) * 4));
        const float4 A1b = *(const float4*)(xb + m1 * 32 + (((c0 + 1) ^ sw) * 4));
        bf16x8 ah0, al0, ah1, al1;
        cvt8(A0a, A0b, ah0, al0);
        cvt8(A1a, A1b, ah1, al1);
        MFMA(ah0, bh0, acc[0][0]); MFMA(ah0, bh1, acc[0][1]);
        MFMA(ah1, bh0, acc[1][0]); MFMA(ah1, bh1, acc[1][1]);
        MFMA(ah0, bl0, acc[0][0]); MFMA(ah0, bl1, acc[0][1]);
        MFMA(ah1, bl0, acc[1][0]); MFMA(ah1, bl1, acc[1][1]);
        MFMA(al0, bh0, acc[0][0]); MFMA(al0, bh1, acc[0][1]);
        MFMA(al1, bh0, acc[1][0]); MFMA(al1, bh1, acc[1][1]);
    };

    // Per-chunk phase: wait(buf c ready, keep newer in flight) -> raw barrier
    // -> B-loads (issued OLDER than next STAGE) -> STAGE(c+2) -> compute.
#define CHUNK(c, VM)                                                          \
    {                                                                         \
        asm volatile("s_waitcnt vmcnt(" VM ")" ::: "memory");                 \
        __builtin_amdgcn_s_barrier();                                         \
        const long f0 = (long)(fbase0 + (c) * 2) * 512;                       \
        const long f1 = f0 + 16 * 512;                                        \
        const long h0 = (long)(fbase0 + (c) * 2 + 1) * 512;                   \
        const long h1 = h0 + 16 * 512;                                        \
        const bf16x8 B0h0 = *(const bf16x8*)(whip + f0);                      \
        const bf16x8 B0l0 = *(const bf16x8*)(wlop + f0);                      \
        const bf16x8 B0h1 = *(const bf16x8*)(whip + f1);                      \
        const bf16x8 B0l1 = *(const bf16x8*)(wlop + f1);                      \
        const bf16x8 B1h0 = *(const bf16x8*)(whip + h0);                      \
        const bf16x8 B1l0 = *(const bf16x8*)(wlop + h0);                      \
        const bf16x8 B1h1 = *(const bf16x8*)(whip + h1);                      \
        const bf16x8 B1l1 = *(const bf16x8*)(wlop + h1);                      \
        __builtin_amdgcn_sched_barrier(0);                                    \
        if ((c) + 2 < 8) STAGE(((c) + 2) % 3, (c) + 2);                       \
        const float* xb = &xs[(c) % 3][0];                                    \
        TSTEP(xb, 0, B0h0, B0l0, B0h1, B0l1);                                 \
        TSTEP(xb, 1, B1h0, B1l0, B1h1, B1l1);                                 \
    }

    STAGE(0, 0);
    STAGE(1, 1);
    CHUNK(0, "2")
    CHUNK(1, "2")
    CHUNK(2, "2")
    CHUNK(3, "2")
    CHUNK(4, "2")
    CHUNK(5, "2")
    CHUNK(6, "2")
    CHUNK(7, "0")
#undef CHUNK

    // Epilogue: bias + ReLU. C/D map (verified m74/m101):
    // col = lane&31, row = (r&3) + 8*(r>>2) + 4*(lane>>5).
    const int  ocol0 = wn * 64;
    const long orow0 = row0 + wm * 64;
    const float bj0 = bias[ocol0 + r31];
    const float bj1 = bias[ocol0 + 32 + r31];

#pragma unroll
    for (int i = 0; i < 2; ++i) {
#pragma unroll
        for (int r = 0; r < 16; ++r) {
            const int rowf = (r & 3) + 8 * (r >> 2) + 4 * g;
            const long row = orow0 + i * 32 + rowf;
            float v0 = acc[i][0][r] + bj0;
            float v1 = acc[i][1][r] + bj1;
            v0 = v0 > 0.f ? v0 : 0.f;
            v1 = v1 > 0.f ? v1 : 0.f;
            out[row * 256 + ocol0 + r31]      = v0;
            out[row * 256 + ocol0 + 32 + r31] = v1;
        }
    }
}

extern "C" void kernel_launch(void* const* d_in, const int* in_sizes, int n_in,
                              void* d_out, int out_size, void* d_ws, size_t ws_size,
                              hipStream_t stream) {
    (void)n_in; (void)ws_size; (void)out_size;
    const float* x = (const float*)d_in[0];
    const float* W = (const float*)d_in[1];
    const float* b = (const float*)d_in[2];
    float* out = (float*)d_out;

    __bf16* whi = (__bf16*)d_ws;             // 128 KB
    __bf16* wlo = whi + 65536;               // 128 KB

    wprep_kernel<<<32, 256, 0, stream>>>(W, whi, wlo);

    const int M = in_sizes[0] / 256;         // 131072
    const int grid = M / 128;                // 1024 row tiles, whole N each
    gemm_mfma_kernel<<<grid, 512, 0, stream>>>(x, whi, wlo, b, out);
}